// Round 4
// baseline (64.128 us; speedup 1.0000x reference)
//
#include <hip/hip_runtime.h>

#define Bn 4
#define Sn 512
#define Hn 128
#define ST 4   // s-rows per attention block

__device__ __forceinline__ float fast_exp2(float x) { return __builtin_amdgcn_exp2f(x); }
__device__ __forceinline__ float fast_rcp(float x)  { return __builtin_amdgcn_rcpf(x); }

#define C2 2.8853900817779268f   // 2*log2(e)

// Kernel 1: eq[b][s][h] = exp2(C2*(q@Wq^T + bias)) ; ekT[b][h][t] = exp2(C2*(k@Wk^T))
// 8 rows per block, 256 blocks.
__global__ __launch_bounds__(256) void proj_kernel(
    const float* __restrict__ query, const float* __restrict__ key,
    const float* __restrict__ attn_W, const float* __restrict__ attn_b,
    float* __restrict__ eq, float* __restrict__ ekT)
{
    __shared__ float rows[2][8][Hn];       // 8 KB
    const int row0 = blockIdx.x * 8;       // global (b*S+s) row
    const int b    = row0 / Sn;
    const int t0   = row0 % Sn;            // multiple of 8
    const int tid  = threadIdx.x;

    // load 2*8*128 floats = 512 float4, 2 per thread
    for (int i = tid; i < 512; i += 256) {
        int src = i >> 8, r = (i >> 5) & 7, c4 = i & 31;
        ((float4*)rows)[i] =
            reinterpret_cast<const float4*>(src ? key : query)[(row0 + r) * 32 + c4];
    }
    __syncthreads();

    const int o     = tid & 127;
    const int which = tid >> 7;            // 0 = q-proj, 1 = k-proj (wave-uniform)
    float acc[8] = {0,0,0,0,0,0,0,0};
    const float* wrow = attn_W + o * (2 * Hn) + which * Hn;
    for (int c = 0; c < Hn; c += 4) {
        float4 wv = *reinterpret_cast<const float4*>(wrow + c);
        #pragma unroll
        for (int r = 0; r < 8; r++) {
            float4 rv = *reinterpret_cast<const float4*>(&rows[which][r][c]); // b128 broadcast
            acc[r] += rv.x * wv.x + rv.y * wv.y + rv.z * wv.z + rv.w * wv.w;
        }
    }
    if (which == 0) {
        float bias = attn_b[o];
        #pragma unroll
        for (int r = 0; r < 8; r++)
            eq[(row0 + r) * Hn + o] = fast_exp2(C2 * (acc[r] + bias));
    } else {
        float4 e0, e1;
        e0.x = fast_exp2(C2 * acc[0]); e0.y = fast_exp2(C2 * acc[1]);
        e0.z = fast_exp2(C2 * acc[2]); e0.w = fast_exp2(C2 * acc[3]);
        e1.x = fast_exp2(C2 * acc[4]); e1.y = fast_exp2(C2 * acc[5]);
        e1.z = fast_exp2(C2 * acc[6]); e1.w = fast_exp2(C2 * acc[7]);
        float* dst = &ekT[(size_t)(b * Hn + o) * Sn + t0];
        *reinterpret_cast<float4*>(dst)     = e0;
        *reinterpret_cast<float4*>(dst + 4) = e1;
    }
}

// Kernel 2: fused scores -> softmax -> PV.
// 1024 threads: thread = (t column, h-half). 2 blocks/CU = 32 waves/CU.
__global__ __launch_bounds__(1024, 8) void attn_kernel(
    const float* __restrict__ eq, const float* __restrict__ ekT,
    const float* __restrict__ value, const float* __restrict__ v_w,
    float* __restrict__ out, float* __restrict__ out_w)
{
    __shared__ float4 qs4[Hn];                // qs4[h] = {eq[s0..s0+3][h]}   2 KB
    __shared__ float4 vw4[Hn / 4];            // -2*v_w packed                0.5 KB
    __shared__ float4 scA[Sn];                // h-half-0 partial logits      8 KB
    __shared__ float4 scB[Sn];                // h-half-1 partial logits      8 KB
    __shared__ float4 part4[16][ST][Hn / 4];  // PV partials                  32 KB

    const int b   = blockIdx.y;
    const int s0  = blockIdx.x * ST;
    const int tid = threadIdx.x;

    if (tid < 512) {
        const int s = tid >> 7, h = tid & 127;
        ((float*)&qs4[h])[s] = eq[(b * Sn + s0 + s) * Hn + h];
    } else if (tid < 512 + Hn) {
        const int h = tid - 512;
        ((float*)vw4)[h] = -2.0f * v_w[h];
    }
    __syncthreads();

    // ---- score phase: each thread does 64 h for one t ----
    {
        const int t    = tid & 511;
        const int half = tid >> 9;            // wave-uniform
        const int hb   = half * 64;
        const float* kb = ekT + (size_t)b * Hn * Sn + (size_t)hb * Sn + t;
        float a0 = 0.f, a1 = 0.f, a2 = 0.f, a3 = 0.f;
        float ek[8];
        #pragma unroll
        for (int j = 0; j < 8; j++) ek[j] = kb[j * Sn];
        for (int g = 0; g < 64; g += 8) {
            float nk[8];
            #pragma unroll
            for (int j = 0; j < 8; j++) nk[j] = (g + 8 < 64) ? kb[(g + 8 + j) * Sn] : 0.0f;
            float4 wA = vw4[((hb + g) >> 2) + 0];
            float4 wB = vw4[((hb + g) >> 2) + 1];
            const float wj[8] = {wA.x, wA.y, wA.z, wA.w, wB.x, wB.y, wB.z, wB.w};
            #pragma unroll
            for (int j = 0; j < 8; j++) {
                float4 q4 = qs4[hb + g + j];   // b128 broadcast
                float w = wj[j];
                a0 += w * fast_rcp(q4.x * ek[j] + 1.0f);
                a1 += w * fast_rcp(q4.y * ek[j] + 1.0f);
                a2 += w * fast_rcp(q4.z * ek[j] + 1.0f);
                a3 += w * fast_rcp(q4.w * ek[j] + 1.0f);
            }
            #pragma unroll
            for (int j = 0; j < 8; j++) ek[j] = nk[j];
        }
        float4 av; av.x = a0; av.y = a1; av.z = a2; av.w = a3;
        (half ? scB : scA)[t] = av;
    }
    __syncthreads();

    // ---- softmax: waves 0..3, one per s-row ----
    {
        const int wave = tid >> 6, lane = tid & 63;
        if (wave < ST) {
            const int sr = wave;
            float v[8]; float m = -1e30f;
            #pragma unroll
            for (int i = 0; i < 8; i++) {
                v[i] = ((const float*)&scA[lane + i * 64])[sr]
                     + ((const float*)&scB[lane + i * 64])[sr];
                m = fmaxf(m, v[i]);
            }
            #pragma unroll
            for (int off = 32; off; off >>= 1) m = fmaxf(m, __shfl_xor(m, off, 64));
            float sum = 0.f;
            const float l2e = 1.4426950408889634f;
            #pragma unroll
            for (int i = 0; i < 8; i++) { v[i] = fast_exp2((v[i] - m) * l2e); sum += v[i]; }
            #pragma unroll
            for (int off = 32; off; off >>= 1) sum += __shfl_xor(sum, off, 64);
            float inv = 1.0f / sum;
            float* wrow_out = out_w + (size_t)(b * Sn + s0 + sr) * Sn;
            #pragma unroll
            for (int i = 0; i < 8; i++) {
                float wgt = v[i] * inv;
                ((float*)&scA[lane + i * 64])[sr] = wgt;   // weights for PV
                wrow_out[lane + i * 64] = wgt;             // coalesced global write
            }
        }
    }
    __syncthreads();

    // ---- PV: threads 0..511 = (tg in 16, hq in 32); value read once per block ----
    if (tid < 512) {
        const int hq = tid & 31, tg = tid >> 5;
        const float* vb = value + ((size_t)b * Sn + tg * 32) * Hn + hq * 4;
        float4 A0 = {0,0,0,0}, A1 = {0,0,0,0}, A2 = {0,0,0,0}, A3 = {0,0,0,0};
        #pragma unroll 4
        for (int i = 0; i < 32; i++) {
            float4 v4 = *reinterpret_cast<const float4*>(vb + i * Hn);
            float4 w4 = scA[tg * 32 + i];     // b128 broadcast
            A0.x += w4.x * v4.x; A0.y += w4.x * v4.y; A0.z += w4.x * v4.z; A0.w += w4.x * v4.w;
            A1.x += w4.y * v4.x; A1.y += w4.y * v4.y; A1.z += w4.y * v4.z; A1.w += w4.y * v4.w;
            A2.x += w4.z * v4.x; A2.y += w4.z * v4.y; A2.z += w4.z * v4.z; A2.w += w4.z * v4.w;
            A3.x += w4.w * v4.x; A3.y += w4.w * v4.y; A3.z += w4.w * v4.z; A3.w += w4.w * v4.w;
        }
        part4[tg][0][hq] = A0;
        part4[tg][1][hq] = A1;
        part4[tg][2][hq] = A2;
        part4[tg][3][hq] = A3;
    }
    __syncthreads();
    if (tid < 512) {
        const int sg = tid >> 7, h = tid & 127;
        float r = 0.f;
        #pragma unroll
        for (int tg = 0; tg < 16; tg++)
            r += ((const float*)&part4[tg][sg][h >> 2])[h & 3];
        out[(b * Sn + s0 + sg) * Hn + h] = r;
    }
}

extern "C" void kernel_launch(void* const* d_in, const int* in_sizes, int n_in,
                              void* d_out, int out_size, void* d_ws, size_t ws_size,
                              hipStream_t stream) {
    const float* query  = (const float*)d_in[0];
    const float* key    = (const float*)d_in[1];
    const float* value  = (const float*)d_in[2];
    const float* attn_W = (const float*)d_in[3];
    const float* attn_b = (const float*)d_in[4];
    const float* v_w    = (const float*)d_in[5];

    float* out   = (float*)d_out;            // (B,S,H) then (B,S,S), both f32
    float* out_w = out + Bn * Sn * Hn;

    float* eq  = (float*)d_ws;               // B*S*H floats = 1 MB
    float* ekT = eq + Bn * Sn * Hn;          // B*H*S floats = 1 MB

    proj_kernel<<<Bn * Sn / 8, 256, 0, stream>>>(query, key, attn_W, attn_b, eq, ekT);
    attn_kernel<<<dim3(Sn / ST, Bn), 1024, 0, stream>>>(eq, ekT, value, v_w, out, out_w);
}

// Round 5
// 38.660 us; speedup vs baseline: 1.6588x; 1.6588x over previous
//
#include <hip/hip_runtime.h>

#define Bn 4
#define Sn 512
#define Hn 128
#define ST 4   // s-rows per score/softpv block

__device__ __forceinline__ float fast_exp2(float x) { return __builtin_amdgcn_exp2f(x); }
__device__ __forceinline__ float fast_rcp(float x)  { return __builtin_amdgcn_rcpf(x); }

#define C2 2.8853900817779268f   // 2*log2(e)

// Kernel 1: eq[b][s][h] = exp2(C2*(q@Wq^T + bias)) ; ekT[b][h][t] = exp2(C2*(k@Wk^T))
__global__ __launch_bounds__(256) void proj_kernel(
    const float* __restrict__ query, const float* __restrict__ key,
    const float* __restrict__ attn_W, const float* __restrict__ attn_b,
    float* __restrict__ eq, float* __restrict__ ekT)
{
    __shared__ float rows[2][8][Hn];       // 8 KB
    const int row0 = blockIdx.x * 8;       // global (b*S+s) row
    const int b    = row0 / Sn;
    const int t0   = row0 % Sn;            // multiple of 8
    const int tid  = threadIdx.x;

    for (int i = tid; i < 512; i += 256) {
        int src = i >> 8, r = (i >> 5) & 7, c4 = i & 31;
        ((float4*)rows)[i] =
            reinterpret_cast<const float4*>(src ? key : query)[(row0 + r) * 32 + c4];
    }
    __syncthreads();

    const int o     = tid & 127;
    const int which = tid >> 7;            // 0 = q-proj, 1 = k-proj (wave-uniform)
    float acc[8] = {0,0,0,0,0,0,0,0};
    const float* wrow = attn_W + o * (2 * Hn) + which * Hn;
    for (int c = 0; c < Hn; c += 4) {
        float4 wv = *reinterpret_cast<const float4*>(wrow + c);
        #pragma unroll
        for (int r = 0; r < 8; r++) {
            float4 rv = *reinterpret_cast<const float4*>(&rows[which][r][c]); // b128 broadcast
            acc[r] += rv.x * wv.x + rv.y * wv.y + rv.z * wv.z + rv.w * wv.w;
        }
    }
    if (which == 0) {
        float bias = attn_b[o];
        #pragma unroll
        for (int r = 0; r < 8; r++)
            eq[(row0 + r) * Hn + o] = fast_exp2(C2 * (acc[r] + bias));
    } else {
        float4 e0, e1;
        e0.x = fast_exp2(C2 * acc[0]); e0.y = fast_exp2(C2 * acc[1]);
        e0.z = fast_exp2(C2 * acc[2]); e0.w = fast_exp2(C2 * acc[3]);
        e1.x = fast_exp2(C2 * acc[4]); e1.y = fast_exp2(C2 * acc[5]);
        e1.z = fast_exp2(C2 * acc[6]); e1.w = fast_exp2(C2 * acc[7]);
        float* dst = &ekT[(size_t)(b * Hn + o) * Sn + t0];
        *reinterpret_cast<float4*>(dst)     = e0;
        *reinterpret_cast<float4*>(dst + 4) = e1;
    }
}

// Kernel 2: raw logits -> out_w region.
// Grid (Sn/ST, Bn, 4 t-quarters) = 2048 blocks x 256 threads.
// Thread = (t in 128-range, h-half). 8 blocks/CU -> 32 waves/CU.
__global__ __launch_bounds__(256) void score_kernel(
    const float* __restrict__ eq, const float* __restrict__ ekT,
    const float* __restrict__ v_w, float* __restrict__ logits)
{
    __shared__ float4 qs4[Hn];       // qs4[h] = {eq[s0..s0+3][h]}  2 KB
    __shared__ float4 vw4[Hn / 4];   // -2*v_w packed               0.5 KB
    __shared__ float4 part4[128];    // h-half-1 partials           2 KB

    const int b   = blockIdx.y;
    const int s0  = blockIdx.x * ST;
    const int t0  = blockIdx.z * 128;
    const int tid = threadIdx.x;

    for (int i = tid; i < 512; i += 256) {
        int s = i >> 7, h = i & 127;
        ((float*)&qs4[h])[s] = eq[(b * Sn + s0 + s) * Hn + h];
    }
    if (tid < Hn) ((float*)vw4)[tid] = -2.0f * v_w[tid];
    __syncthreads();

    const int tl = tid & 127;        // t within this 128-wide tile
    const int hh = tid >> 7;         // h-half (wave-uniform)
    const int hb = hh * 64;
    const float* kb = ekT + (size_t)b * Hn * Sn + (size_t)hb * Sn + (t0 + tl);
    float a0 = 0.f, a1 = 0.f, a2 = 0.f, a3 = 0.f;
    float ek[8];
    #pragma unroll
    for (int j = 0; j < 8; j++) ek[j] = kb[j * Sn];
    #pragma unroll
    for (int g = 0; g < 64; g += 8) {
        float nk[8];
        #pragma unroll
        for (int j = 0; j < 8; j++) nk[j] = (g + 8 < 64) ? kb[(g + 8 + j) * Sn] : 0.0f;
        float4 wA = vw4[((hb + g) >> 2) + 0];
        float4 wB = vw4[((hb + g) >> 2) + 1];
        const float wj[8] = {wA.x, wA.y, wA.z, wA.w, wB.x, wB.y, wB.z, wB.w};
        #pragma unroll
        for (int j = 0; j < 8; j++) {
            float4 q4 = qs4[hb + g + j];   // b128 broadcast
            float w = wj[j];
            a0 += w * fast_rcp(q4.x * ek[j] + 1.0f);
            a1 += w * fast_rcp(q4.y * ek[j] + 1.0f);
            a2 += w * fast_rcp(q4.z * ek[j] + 1.0f);
            a3 += w * fast_rcp(q4.w * ek[j] + 1.0f);
        }
        #pragma unroll
        for (int j = 0; j < 8; j++) ek[j] = nk[j];
    }
    if (hh) {
        float4 av; av.x = a0; av.y = a1; av.z = a2; av.w = a3;
        part4[tl] = av;
    }
    __syncthreads();
    if (!hh) {
        float4 p = part4[tl];
        a0 += p.x; a1 += p.y; a2 += p.z; a3 += p.w;
        float* Lrow = logits + (size_t)(b * Sn + s0) * Sn + t0 + tl;
        Lrow[0 * Sn] = a0; Lrow[1 * Sn] = a1; Lrow[2 * Sn] = a2; Lrow[3 * Sn] = a3;
    }
}

// Kernel 3: softmax (in-place on out_w) + PV.  512 threads, grid (Sn/ST, Bn).
__global__ __launch_bounds__(512) void softpv_kernel(
    const float* __restrict__ value, float* __restrict__ out,
    float* __restrict__ out_w)
{
    __shared__ float4 scT4[Sn];               // weights transposed  8 KB
    __shared__ float4 part4[16][ST][Hn / 4];  // PV partials        32 KB

    const int b   = blockIdx.y;
    const int s0  = blockIdx.x * ST;
    const int tid = threadIdx.x;
    const int wave = tid >> 6, lane = tid & 63;

    if (wave < ST) {
        const int sr = wave;
        float* row = out_w + (size_t)(b * Sn + s0 + sr) * Sn;
        float v[8]; float m = -1e30f;
        #pragma unroll
        for (int i = 0; i < 8; i++) { v[i] = row[lane + i * 64]; m = fmaxf(m, v[i]); }
        #pragma unroll
        for (int off = 32; off; off >>= 1) m = fmaxf(m, __shfl_xor(m, off, 64));
        float sum = 0.f;
        const float l2e = 1.4426950408889634f;
        #pragma unroll
        for (int i = 0; i < 8; i++) { v[i] = fast_exp2((v[i] - m) * l2e); sum += v[i]; }
        #pragma unroll
        for (int off = 32; off; off >>= 1) sum += __shfl_xor(sum, off, 64);
        float inv = 1.0f / sum;
        #pragma unroll
        for (int i = 0; i < 8; i++) {
            float wgt = v[i] * inv;
            row[lane + i * 64] = wgt;                  // normalized weights out
            ((float*)&scT4[lane + i * 64])[sr] = wgt;  // transposed copy for PV
        }
    }
    __syncthreads();

    // PV: thread = (tg in 16, hq in 32); value read once per block
    {
        const int hq = tid & 31, tg = tid >> 5;
        const float* vb = value + ((size_t)b * Sn + tg * 32) * Hn + hq * 4;
        float4 A0 = {0,0,0,0}, A1 = {0,0,0,0}, A2 = {0,0,0,0}, A3 = {0,0,0,0};
        #pragma unroll 4
        for (int i = 0; i < 32; i++) {
            float4 v4 = *reinterpret_cast<const float4*>(vb + i * Hn);
            float4 w4 = scT4[tg * 32 + i];     // b128 broadcast
            A0.x += w4.x * v4.x; A0.y += w4.x * v4.y; A0.z += w4.x * v4.z; A0.w += w4.x * v4.w;
            A1.x += w4.y * v4.x; A1.y += w4.y * v4.y; A1.z += w4.y * v4.z; A1.w += w4.y * v4.w;
            A2.x += w4.z * v4.x; A2.y += w4.z * v4.y; A2.z += w4.z * v4.z; A2.w += w4.z * v4.w;
            A3.x += w4.w * v4.x; A3.y += w4.w * v4.y; A3.z += w4.w * v4.z; A3.w += w4.w * v4.w;
        }
        part4[tg][0][hq] = A0;
        part4[tg][1][hq] = A1;
        part4[tg][2][hq] = A2;
        part4[tg][3][hq] = A3;
    }
    __syncthreads();
    {
        const int sg = tid >> 7, h = tid & 127;
        float r = 0.f;
        #pragma unroll
        for (int tg = 0; tg < 16; tg++)
            r += ((const float*)&part4[tg][sg][h >> 2])[h & 3];
        out[(b * Sn + s0 + sg) * Hn + h] = r;
    }
}

extern "C" void kernel_launch(void* const* d_in, const int* in_sizes, int n_in,
                              void* d_out, int out_size, void* d_ws, size_t ws_size,
                              hipStream_t stream) {
    const float* query  = (const float*)d_in[0];
    const float* key    = (const float*)d_in[1];
    const float* value  = (const float*)d_in[2];
    const float* attn_W = (const float*)d_in[3];
    const float* attn_b = (const float*)d_in[4];
    const float* v_w    = (const float*)d_in[5];

    float* out   = (float*)d_out;            // (B,S,H) then (B,S,S), both f32
    float* out_w = out + Bn * Sn * Hn;

    float* eq  = (float*)d_ws;               // B*S*H floats = 1 MB
    float* ekT = eq + Bn * Sn * Hn;          // B*H*S floats = 1 MB

    proj_kernel<<<Bn * Sn / 8, 256, 0, stream>>>(query, key, attn_W, attn_b, eq, ekT);
    score_kernel<<<dim3(Sn / ST, Bn, 4), 256, 0, stream>>>(eq, ekT, v_w, out_w);
    softpv_kernel<<<dim3(Sn / ST, Bn), 512, 0, stream>>>(value, out, out_w);
}